// Round 1
// 276.709 us; speedup vs baseline: 1.0783x; 1.0783x over previous
//
#include <hip/hip_runtime.h>
#include <hip/hip_bf16.h>

// TransformerBlock: B=8,S=196,D=768,H=12,HD=64,E=8,FF=3072. T = B*S = 1568 tokens.
//
// Exact simplifications:
//  - attention: k,v broadcast across heads -> logits constant over softmax axis
//    -> softmax uniform -> attn_out = tile(v). Wq/bq/Wk/bk/RoPE are dead code.
//  - MoE top-1 = argmax of gating logits (softmax monotone).
//
// R2 structure:
//  - k_front fuses LN1 + v-projection + (x2 = x+tile(v), LN2, gate, bucketize,
//    out init = x2 + b2[expert]) into ONE kernel: h1 lives in LDS (fp32),
//    v lives in registers; x is loaded once. 6 dispatches -> 4.
//  - Both MoE GEMMs: BM=128, BN=64, BK=64, DEPTH-2 register prefetch (two
//    named reg sets, static indexing) so global-load issue -> LDS-write use
//    distance ~2 k-tiles (~1000cy) >= HBM latency. B fp32->bf16 via
//    __float2bfloat16 (compiler emits v_cvt_pk_bf16_f32).
//  - GEMM2 is split-K x4, atomicAdd fp32 partials onto the pre-initialized out.

typedef unsigned short u16;
typedef short bf16x8_t __attribute__((ext_vector_type(8)));
typedef float f32x4_t  __attribute__((ext_vector_type(4)));

#define T_TOK 1568
#define DM 768
#define HD 64
#define FF 3072
#define NE 8

// workspace layout (16B-aligned offsets; ~12.1 MB total)
#define OFF_CNT   0
#define OFF_BUCK  256
#define OFF_H2    (OFF_BUCK + NE*T_TOK*4)
#define OFF_HMID  (OFF_H2 + T_TOK*DM*2)

__device__ __forceinline__ u16 f2bf(float f) {  // RNE via HW cvt
    return __builtin_bit_cast(u16, __float2bfloat16(f));
}
__device__ __forceinline__ float gelu_f(float x) {
    return 0.5f * x * (1.0f + erff(x * 0.70710678118654752440f));
}

// ---------------- K1: fused LN1 -> vproj -> x2/LN2/gate/out-init ----------------
// 8 tokens per block, 196 blocks. Wave w owns tokens w*2, w*2+1 in phases A/C;
// phase B (vproj) splits K across waves exactly like the old k_vproj.
__global__ __launch_bounds__(256) void k_front(
        const float* __restrict__ x,
        const float* __restrict__ g1, const float* __restrict__ b1,
        const float* __restrict__ Wv, const float* __restrict__ bv,
        const float* __restrict__ g2, const float* __restrict__ b2g,
        const float* __restrict__ Wg, const float* __restrict__ bg,
        const float* __restrict__ b2moe,
        u16* __restrict__ h2, float* __restrict__ out,
        int* __restrict__ cnt, int* __restrict__ buck) {
    __shared__ float h1s[8 * DM];     // 24 KB, fp32 LN1 output
    __shared__ float ps[4 * 8 * 64];  // 8 KB, vproj partials
    __shared__ float wgs[NE * DM];    // 24 KB, Wg transposed
    __shared__ float g2s[DM], b2s[DM];
    int tid = threadIdx.x, tb = blockIdx.x * 8;
    int lane = tid & 63, w = tid >> 6;

    // stage gate weights + LN2 params (consumed after barriers)
    for (int idx = tid; idx < NE * DM; idx += 256) {
        int e = idx / DM, c = idx % DM;
        wgs[idx] = Wg[(size_t)c * NE + e];
    }
    for (int idx = tid; idx < DM; idx += 256) { g2s[idx] = g2[idx]; b2s[idx] = b2g[idx]; }

    // ---- phase A: LN1; keep raw x in regs, write h1 (fp32) to LDS ----
    float xa[2][12];
#pragma unroll
    for (int ttl = 0; ttl < 2; ttl++) {
        int t = tb + w * 2 + ttl;
        const float* xp = x + (size_t)t * DM;
        float s = 0.0f;
#pragma unroll
        for (int i = 0; i < 12; i++) { float q = xp[lane + 64 * i]; xa[ttl][i] = q; s += q; }
#pragma unroll
        for (int m = 1; m < 64; m <<= 1) s += __shfl_xor(s, m);
        float mu = s * (1.0f / DM);
        float vs = 0.0f;
#pragma unroll
        for (int i = 0; i < 12; i++) { float d = xa[ttl][i] - mu; vs += d * d; }
#pragma unroll
        for (int m = 1; m < 64; m <<= 1) vs += __shfl_xor(vs, m);
        float rs = rsqrtf(vs * (1.0f / DM) + 1e-5f);
        float* hp = h1s + (size_t)(w * 2 + ttl) * DM;
#pragma unroll
        for (int i = 0; i < 12; i++) {
            int c = lane + 64 * i;
            hp[c] = (xa[ttl][i] - mu) * rs * g1[c] + b1[c];
        }
    }
    __syncthreads();

    // ---- phase B: v = h1 @ Wv (wave w covers k in [w*192, w*192+192)) ----
    {
        float acc[8];
#pragma unroll
        for (int tt = 0; tt < 8; tt++) acc[tt] = 0.0f;
        const float* wp = Wv + (size_t)(w * 192) * HD + lane;
#pragma unroll 2
        for (int kk = 0; kk < 192; kk += 4) {
            float w0 = wp[(size_t)(kk + 0) * HD];
            float w1 = wp[(size_t)(kk + 1) * HD];
            float w2 = wp[(size_t)(kk + 2) * HD];
            float w3 = wp[(size_t)(kk + 3) * HD];
            int kb = w * 192 + kk;
#pragma unroll
            for (int tt = 0; tt < 8; tt++) {
                f32x4_t hv = *(const f32x4_t*)&h1s[tt * DM + kb];  // broadcast read
                acc[tt] += hv[0] * w0 + hv[1] * w1 + hv[2] * w2 + hv[3] * w3;
            }
        }
#pragma unroll
        for (int tt = 0; tt < 8; tt++) ps[(w * 8 + tt) * 64 + lane] = acc[tt];
    }
    __syncthreads();
    float vred[2];
#pragma unroll
    for (int s2 = 0; s2 < 2; s2++) {
        int tt = w * 2 + s2;
        vred[s2] = ps[tt * 64 + lane] + ps[(8 + tt) * 64 + lane] +
                   ps[(16 + tt) * 64 + lane] + ps[(24 + tt) * 64 + lane] + bv[lane];
    }

    // ---- phase C: x2 = x + tile(v); LN2 -> h2; gate argmax; out init ----
#pragma unroll
    for (int ttl = 0; ttl < 2; ttl++) {
        int t = tb + w * 2 + ttl;
        float vl = vred[ttl];    // v col index = c % 64 == lane
        float xv[12];
        float s = 0.0f;
#pragma unroll
        for (int i = 0; i < 12; i++) { float q = xa[ttl][i] + vl; xv[i] = q; s += q; }
#pragma unroll
        for (int m = 1; m < 64; m <<= 1) s += __shfl_xor(s, m);
        float mu = s * (1.0f / DM);
        float vs = 0.0f;
#pragma unroll
        for (int i = 0; i < 12; i++) { float d = xv[i] - mu; vs += d * d; }
#pragma unroll
        for (int m = 1; m < 64; m <<= 1) vs += __shfl_xor(vs, m);
        float rs = rsqrtf(vs * (1.0f / DM) + 1e-5f);
        float le[NE];
#pragma unroll
        for (int e = 0; e < NE; e++) le[e] = 0.0f;
        u16* h2p = h2 + (size_t)t * DM;
#pragma unroll
        for (int i = 0; i < 12; i++) {
            int c = lane + 64 * i;
            float h = (xv[i] - mu) * rs * g2s[c] + b2s[c];
            h2p[c] = f2bf(h);
#pragma unroll
            for (int e = 0; e < NE; e++) le[e] += h * wgs[e * DM + c];
        }
#pragma unroll
        for (int e = 0; e < NE; e++) {
#pragma unroll
            for (int m = 1; m < 64; m <<= 1) le[e] += __shfl_xor(le[e], m);
        }
        // all lanes hold bitwise-identical le[] (butterfly) -> uniform argmax
        float best = le[0] + bg[0]; int be = 0;
#pragma unroll
        for (int e = 1; e < NE; e++) {
            float q = le[e] + bg[e];
            if (q > best) { best = q; be = e; }   // strict > == first-max (jnp.argmax)
        }
        if (lane == 0) {
            int pos = atomicAdd(&cnt[be], 1);
            buck[be * T_TOK + pos] = t;
        }
        // out init: x2 + b2[be]  (gemm2 atomicAdds the MoE matmul on top)
        float* op = out + (size_t)t * DM;
        const float* bp = b2moe + (size_t)be * DM;
#pragma unroll
        for (int i = 0; i < 12; i++) {
            int c = lane + 64 * i;
            op[c] = xv[i] + bp[c];
        }
    }
}

// ---------------- K2: grouped GEMM1 + gelu: hmid = gelu(h2 @ W1[e] + b1[e]) ----------------
// BM=128, BN=64, BK=64; 4 waves, wave -> 32-row strip x 64 cols.
// DEPTH-2 register prefetch: sets P/Q; issue(kt+2) -> use distance ~2 k-tiles.
__global__ __launch_bounds__(256, 3) void k_moe_gemm1(
        const u16* __restrict__ h2, const float* __restrict__ W1,
        const float* __restrict__ b1, const int* __restrict__ cnt,
        const int* __restrict__ buck, u16* __restrict__ hmid) {
    int nt = blockIdx.x, e = blockIdx.y, mt = blockIdx.z;
    int cnte = cnt[e];
    int m0 = mt * 128;
    if (m0 >= cnte) return;
    int n0 = nt * 64;
    const float* W1e = W1 + (size_t)e * DM * FF;
    __shared__ __align__(16) u16 As[128 * 72];   // 18 KB
    __shared__ __align__(16) u16 Bs[64 * 72];    // 9 KB, [n][k]
    int tid = threadIdx.x, lane = tid & 63, wid = tid >> 6;

    int arow = tid >> 3, ac = tid & 7;
    int atok[4];
#pragma unroll
    for (int j = 0; j < 4; j++) {
        int i = m0 + arow + 32 * j;
        atok[j] = (i < cnte) ? buck[e * T_TOK + i] : -1;
    }
    int bn = tid & 63, bkg = tid >> 6;

    f32x4_t acc[2][4];
#pragma unroll
    for (int mi = 0; mi < 2; mi++)
#pragma unroll
        for (int ni = 0; ni < 4; ni++) acc[mi][ni] = (f32x4_t){0.f, 0.f, 0.f, 0.f};

    bf16x8_t aP[4], aQ[4];
    float bP[16], bQ[16];

#define G_LOAD(SA, SB, KT) { \
    int k0_ = (KT) * 64; \
    _Pragma("unroll") \
    for (int j = 0; j < 4; j++) { \
        bf16x8_t v_ = {0, 0, 0, 0, 0, 0, 0, 0}; \
        if (atok[j] >= 0) v_ = *(const bf16x8_t*)&h2[(size_t)atok[j] * DM + k0_ + ac * 8]; \
        SA[j] = v_; \
    } \
    const float* bp_ = W1e + (size_t)(k0_ + bkg * 16) * FF + n0 + bn; \
    _Pragma("unroll") \
    for (int kk = 0; kk < 16; kk++) SB[kk] = bp_[(size_t)kk * FF]; \
}
#define STORE_LDS(SA, SB) { \
    _Pragma("unroll") \
    for (int j = 0; j < 4; j++) \
        *(bf16x8_t*)&As[(arow + 32 * j) * 72 + ac * 8] = SA[j]; \
    bf16x8_t p0_, p1_; \
    _Pragma("unroll") \
    for (int kk = 0; kk < 8; kk++) { \
        p0_[kk] = (short)f2bf(SB[kk]); \
        p1_[kk] = (short)f2bf(SB[kk + 8]); \
    } \
    *(bf16x8_t*)&Bs[bn * 72 + bkg * 16] = p0_; \
    *(bf16x8_t*)&Bs[bn * 72 + bkg * 16 + 8] = p1_; \
}
#define MFMA_TILE() { \
    int lr_ = lane & 15, q_ = lane >> 4; \
    _Pragma("unroll") \
    for (int s = 0; s < 2; s++) { \
        bf16x8_t af[2], bfr[4]; \
        _Pragma("unroll") \
        for (int mi = 0; mi < 2; mi++) \
            af[mi] = *(const bf16x8_t*)&As[(wid * 32 + mi * 16 + lr_) * 72 + s * 32 + q_ * 8]; \
        _Pragma("unroll") \
        for (int ni = 0; ni < 4; ni++) \
            bfr[ni] = *(const bf16x8_t*)&Bs[(ni * 16 + lr_) * 72 + s * 32 + q_ * 8]; \
        _Pragma("unroll") \
        for (int mi = 0; mi < 2; mi++) \
            _Pragma("unroll") \
            for (int ni = 0; ni < 4; ni++) \
                acc[mi][ni] = __builtin_amdgcn_mfma_f32_16x16x32_bf16( \
                    af[mi], bfr[ni], acc[mi][ni], 0, 0, 0); \
    } \
}

    G_LOAD(aP, bP, 0)
    G_LOAD(aQ, bQ, 1)
    for (int kt = 0; kt < 12; kt += 2) {
        __syncthreads();
        STORE_LDS(aP, bP)
        __syncthreads();
        if (kt + 2 < 12) G_LOAD(aP, bP, kt + 2)
        MFMA_TILE()
        __syncthreads();
        STORE_LDS(aQ, bQ)
        __syncthreads();
        if (kt + 3 < 12) G_LOAD(aQ, bQ, kt + 3)
        MFMA_TILE()
    }
#undef G_LOAD
#undef STORE_LDS
#undef MFMA_TILE

    // epilogue: bias + gelu, scatter by token id
    int lr = lane & 15, q = lane >> 4;
    float bias[4];
#pragma unroll
    for (int ni = 0; ni < 4; ni++) bias[ni] = b1[(size_t)e * FF + n0 + ni * 16 + lr];
#pragma unroll
    for (int mi = 0; mi < 2; mi++) {
#pragma unroll
        for (int r = 0; r < 4; r++) {
            int i = m0 + wid * 32 + mi * 16 + q * 4 + r;
            if (i < cnte) {
                int t = buck[e * T_TOK + i];
                size_t base = (size_t)t * FF + n0;
#pragma unroll
                for (int ni = 0; ni < 4; ni++) {
                    float vv = acc[mi][ni][r] + bias[ni];
                    hmid[base + ni * 16 + lr] = f2bf(gelu_f(vv));
                }
            }
        }
    }
}

// ---------------- K3: grouped GEMM2 split-K x4: out += hmid @ W2[e] ----------------
// BM=128, BN=64, BK=64, K-chunk = FF/4 = 768. z = mt*4 + kc. Depth-2 prefetch.
__global__ __launch_bounds__(256, 3) void k_moe_gemm2(
        const u16* __restrict__ hmid, const float* __restrict__ W2,
        const int* __restrict__ cnt, const int* __restrict__ buck,
        float* __restrict__ out) {
    int nt = blockIdx.x, e = blockIdx.y, z = blockIdx.z;
    int kc = z & 3, mt = z >> 2;
    int cnte = cnt[e];
    int m0 = mt * 128;
    if (m0 >= cnte) return;
    int n0 = nt * 64;
    int kbase = kc * (FF / 4);
    const float* W2e = W2 + (size_t)e * FF * DM;
    __shared__ __align__(16) u16 As[128 * 72];
    __shared__ __align__(16) u16 Bs[64 * 72];
    int tid = threadIdx.x, lane = tid & 63, wid = tid >> 6;

    int arow = tid >> 3, ac = tid & 7;
    int atok[4];
#pragma unroll
    for (int j = 0; j < 4; j++) {
        int i = m0 + arow + 32 * j;
        atok[j] = (i < cnte) ? buck[e * T_TOK + i] : -1;
    }
    int bn = tid & 63, bkg = tid >> 6;

    f32x4_t acc[2][4];
#pragma unroll
    for (int mi = 0; mi < 2; mi++)
#pragma unroll
        for (int ni = 0; ni < 4; ni++) acc[mi][ni] = (f32x4_t){0.f, 0.f, 0.f, 0.f};

    bf16x8_t aP[4], aQ[4];
    float bP[16], bQ[16];

#define G_LOAD(SA, SB, KT) { \
    int k0_ = kbase + (KT) * 64; \
    _Pragma("unroll") \
    for (int j = 0; j < 4; j++) { \
        bf16x8_t v_ = {0, 0, 0, 0, 0, 0, 0, 0}; \
        if (atok[j] >= 0) v_ = *(const bf16x8_t*)&hmid[(size_t)atok[j] * FF + k0_ + ac * 8]; \
        SA[j] = v_; \
    } \
    const float* bp_ = W2e + (size_t)(k0_ + bkg * 16) * DM + n0 + bn; \
    _Pragma("unroll") \
    for (int kk = 0; kk < 16; kk++) SB[kk] = bp_[(size_t)kk * DM]; \
}
#define STORE_LDS(SA, SB) { \
    _Pragma("unroll") \
    for (int j = 0; j < 4; j++) \
        *(bf16x8_t*)&As[(arow + 32 * j) * 72 + ac * 8] = SA[j]; \
    bf16x8_t p0_, p1_; \
    _Pragma("unroll") \
    for (int kk = 0; kk < 8; kk++) { \
        p0_[kk] = (short)f2bf(SB[kk]); \
        p1_[kk] = (short)f2bf(SB[kk + 8]); \
    } \
    *(bf16x8_t*)&Bs[bn * 72 + bkg * 16] = p0_; \
    *(bf16x8_t*)&Bs[bn * 72 + bkg * 16 + 8] = p1_; \
}
#define MFMA_TILE() { \
    int lr_ = lane & 15, q_ = lane >> 4; \
    _Pragma("unroll") \
    for (int s = 0; s < 2; s++) { \
        bf16x8_t af[2], bfr[4]; \
        _Pragma("unroll") \
        for (int mi = 0; mi < 2; mi++) \
            af[mi] = *(const bf16x8_t*)&As[(wid * 32 + mi * 16 + lr_) * 72 + s * 32 + q_ * 8]; \
        _Pragma("unroll") \
        for (int ni = 0; ni < 4; ni++) \
            bfr[ni] = *(const bf16x8_t*)&Bs[(ni * 16 + lr_) * 72 + s * 32 + q_ * 8]; \
        _Pragma("unroll") \
        for (int mi = 0; mi < 2; mi++) \
            _Pragma("unroll") \
            for (int ni = 0; ni < 4; ni++) \
                acc[mi][ni] = __builtin_amdgcn_mfma_f32_16x16x32_bf16( \
                    af[mi], bfr[ni], acc[mi][ni], 0, 0, 0); \
    } \
}

    G_LOAD(aP, bP, 0)
    G_LOAD(aQ, bQ, 1)
    for (int kt = 0; kt < 12; kt += 2) {
        __syncthreads();
        STORE_LDS(aP, bP)
        __syncthreads();
        if (kt + 2 < 12) G_LOAD(aP, bP, kt + 2)
        MFMA_TILE()
        __syncthreads();
        STORE_LDS(aQ, bQ)
        __syncthreads();
        if (kt + 3 < 12) G_LOAD(aQ, bQ, kt + 3)
        MFMA_TILE()
    }
#undef G_LOAD
#undef STORE_LDS
#undef MFMA_TILE

    // epilogue: atomicAdd partials into out (out pre-initialized with x2 + b2[e])
    int lr = lane & 15, q = lane >> 4;
#pragma unroll
    for (int mi = 0; mi < 2; mi++) {
#pragma unroll
        for (int r = 0; r < 4; r++) {
            int i = m0 + wid * 32 + mi * 16 + q * 4 + r;
            if (i < cnte) {
                int t = buck[e * T_TOK + i];
                size_t base = (size_t)t * DM + n0;
#pragma unroll
                for (int ni = 0; ni < 4; ni++)
                    atomicAdd(&out[base + ni * 16 + lr], acc[mi][ni][r]);
            }
        }
    }
}

extern "C" void kernel_launch(void* const* d_in, const int* in_sizes, int n_in,
                              void* d_out, int out_size, void* d_ws, size_t ws_size,
                              hipStream_t stream) {
    const float* x    = (const float*)d_in[0];
    const float* ln1g = (const float*)d_in[1];
    const float* ln1b = (const float*)d_in[2];
    // d_in[3..6] = Wq,bq,Wk,bk: dead code
    const float* Wv   = (const float*)d_in[7];
    const float* bv   = (const float*)d_in[8];
    const float* ln2g = (const float*)d_in[9];
    const float* ln2b = (const float*)d_in[10];
    const float* Wg   = (const float*)d_in[11];
    const float* bg   = (const float*)d_in[12];
    const float* W1   = (const float*)d_in[13];
    const float* b1   = (const float*)d_in[14];
    const float* W2   = (const float*)d_in[15];
    const float* b2   = (const float*)d_in[16];

    char* ws = (char*)d_ws;
    int*   cnt  = (int*)(ws + OFF_CNT);
    int*   buck = (int*)(ws + OFF_BUCK);
    u16*   h2   = (u16*)(ws + OFF_H2);
    u16*   hmid = (u16*)(ws + OFF_HMID);
    float* out  = (float*)d_out;

    hipMemsetAsync(cnt, 0, NE * sizeof(int), stream);
    k_front<<<T_TOK / 8, 256, 0, stream>>>(x, ln1g, ln1b, Wv, bv, ln2g, ln2b,
                                           Wg, bg, b2, h2, out, cnt, buck);
    k_moe_gemm1<<<dim3(FF / 64, NE, 13), 256, 0, stream>>>(h2, W1, b1, cnt, buck, hmid);
    k_moe_gemm2<<<dim3(DM / 64, NE, 52), 256, 0, stream>>>(hmid, W2, cnt, buck, out);
}

// Round 2
// 276.209 us; speedup vs baseline: 1.0803x; 1.0018x over previous
//
#include <hip/hip_runtime.h>
#include <hip/hip_bf16.h>

// TransformerBlock: B=8,S=196,D=768,H=12,HD=64,E=8,FF=3072. T = B*S = 1568 tokens.
//
// Exact simplifications:
//  - attention: k,v broadcast across heads -> logits constant over softmax axis
//    -> softmax uniform -> attn_out = tile(v). Wq/bq/Wk/bk/RoPE are dead code.
//  - MoE top-1 = argmax of gating logits (softmax monotone).
//
// R3 structure:
//  - k_front fuses LN1 + v-projection + (x2, LN2, gate, bucketize, out init).
//  - Both MoE GEMMs: BM=128, BN=64, BK=64, depth-2 register prefetch (P/Q sets)
//    with RAW s_barrier (NOT __syncthreads): __syncthreads drains vmcnt(0) and
//    was defeating the prefetch (R2 post-mortem: BW stuck at 2.1 TB/s, both
//    pipes <10%). Raw barrier + own-wave lgkmcnt(0) after LDS stores keeps the
//    other prefetch set's 20 vmem loads in flight across barriers (T3/T4).
//    sched_barrier(0) fences pin LDS ops to their phase. A-token indices are
//    clamped (not branch-guarded) so loads are unconditional; garbage rows are
//    computed but never stored.
//  - GEMM2 is split-K x4, atomicAdd fp32 partials onto the pre-initialized out.

typedef unsigned short u16;
typedef short bf16x8_t __attribute__((ext_vector_type(8)));
typedef float f32x4_t  __attribute__((ext_vector_type(4)));

#define T_TOK 1568
#define DM 768
#define HD 64
#define FF 3072
#define NE 8

// workspace layout (16B-aligned offsets; ~12.1 MB total)
#define OFF_CNT   0
#define OFF_BUCK  256
#define OFF_H2    (OFF_BUCK + NE*T_TOK*4)
#define OFF_HMID  (OFF_H2 + T_TOK*DM*2)

__device__ __forceinline__ u16 f2bf(float f) {  // RNE via HW cvt
    return __builtin_bit_cast(u16, __float2bfloat16(f));
}
__device__ __forceinline__ float gelu_f(float x) {
    return 0.5f * x * (1.0f + erff(x * 0.70710678118654752440f));
}

#define SFENCE() __builtin_amdgcn_sched_barrier(0)
#define RAW_BAR() __builtin_amdgcn_s_barrier()

// ---------------- K1: fused LN1 -> vproj -> x2/LN2/gate/out-init ----------------
// 8 tokens per block, 196 blocks. Wave w owns tokens w*2, w*2+1 in phases A/C;
// phase B (vproj) splits K across waves.
__global__ __launch_bounds__(256) void k_front(
        const float* __restrict__ x,
        const float* __restrict__ g1, const float* __restrict__ b1,
        const float* __restrict__ Wv, const float* __restrict__ bv,
        const float* __restrict__ g2, const float* __restrict__ b2g,
        const float* __restrict__ Wg, const float* __restrict__ bg,
        const float* __restrict__ b2moe,
        u16* __restrict__ h2, float* __restrict__ out,
        int* __restrict__ cnt, int* __restrict__ buck) {
    __shared__ float h1s[8 * DM];     // 24 KB, fp32 LN1 output
    __shared__ float ps[4 * 8 * 64];  // 8 KB, vproj partials
    __shared__ float wgs[NE * DM];    // 24 KB, Wg transposed
    __shared__ float g2s[DM], b2s[DM];
    int tid = threadIdx.x, tb = blockIdx.x * 8;
    int lane = tid & 63, w = tid >> 6;

    // stage gate weights + LN2 params (consumed after barriers)
    for (int idx = tid; idx < NE * DM; idx += 256) {
        int e = idx / DM, c = idx % DM;
        wgs[idx] = Wg[(size_t)c * NE + e];
    }
    for (int idx = tid; idx < DM; idx += 256) { g2s[idx] = g2[idx]; b2s[idx] = b2g[idx]; }

    // ---- phase A: LN1; keep raw x in regs, write h1 (fp32) to LDS ----
    float xa[2][12];
#pragma unroll
    for (int ttl = 0; ttl < 2; ttl++) {
        int t = tb + w * 2 + ttl;
        const float* xp = x + (size_t)t * DM;
        float s = 0.0f;
#pragma unroll
        for (int i = 0; i < 12; i++) { float q = xp[lane + 64 * i]; xa[ttl][i] = q; s += q; }
#pragma unroll
        for (int m = 1; m < 64; m <<= 1) s += __shfl_xor(s, m);
        float mu = s * (1.0f / DM);
        float vs = 0.0f;
#pragma unroll
        for (int i = 0; i < 12; i++) { float d = xa[ttl][i] - mu; vs += d * d; }
#pragma unroll
        for (int m = 1; m < 64; m <<= 1) vs += __shfl_xor(vs, m);
        float rs = rsqrtf(vs * (1.0f / DM) + 1e-5f);
        float* hp = h1s + (size_t)(w * 2 + ttl) * DM;
#pragma unroll
        for (int i = 0; i < 12; i++) {
            int c = lane + 64 * i;
            hp[c] = (xa[ttl][i] - mu) * rs * g1[c] + b1[c];
        }
    }
    __syncthreads();

    // ---- phase B: v = h1 @ Wv (wave w covers k in [w*192, w*192+192)) ----
    {
        float acc[8];
#pragma unroll
        for (int tt = 0; tt < 8; tt++) acc[tt] = 0.0f;
        const float* wp = Wv + (size_t)(w * 192) * HD + lane;
#pragma unroll 2
        for (int kk = 0; kk < 192; kk += 4) {
            float w0 = wp[(size_t)(kk + 0) * HD];
            float w1 = wp[(size_t)(kk + 1) * HD];
            float w2 = wp[(size_t)(kk + 2) * HD];
            float w3 = wp[(size_t)(kk + 3) * HD];
            int kb = w * 192 + kk;
#pragma unroll
            for (int tt = 0; tt < 8; tt++) {
                f32x4_t hv = *(const f32x4_t*)&h1s[tt * DM + kb];  // broadcast read
                acc[tt] += hv[0] * w0 + hv[1] * w1 + hv[2] * w2 + hv[3] * w3;
            }
        }
#pragma unroll
        for (int tt = 0; tt < 8; tt++) ps[(w * 8 + tt) * 64 + lane] = acc[tt];
    }
    __syncthreads();
    float vred[2];
#pragma unroll
    for (int s2 = 0; s2 < 2; s2++) {
        int tt = w * 2 + s2;
        vred[s2] = ps[tt * 64 + lane] + ps[(8 + tt) * 64 + lane] +
                   ps[(16 + tt) * 64 + lane] + ps[(24 + tt) * 64 + lane] + bv[lane];
    }

    // ---- phase C: x2 = x + tile(v); LN2 -> h2; gate argmax; out init ----
#pragma unroll
    for (int ttl = 0; ttl < 2; ttl++) {
        int t = tb + w * 2 + ttl;
        float vl = vred[ttl];    // v col index = c % 64 == lane
        float xv[12];
        float s = 0.0f;
#pragma unroll
        for (int i = 0; i < 12; i++) { float q = xa[ttl][i] + vl; xv[i] = q; s += q; }
#pragma unroll
        for (int m = 1; m < 64; m <<= 1) s += __shfl_xor(s, m);
        float mu = s * (1.0f / DM);
        float vs = 0.0f;
#pragma unroll
        for (int i = 0; i < 12; i++) { float d = xv[i] - mu; vs += d * d; }
#pragma unroll
        for (int m = 1; m < 64; m <<= 1) vs += __shfl_xor(vs, m);
        float rs = rsqrtf(vs * (1.0f / DM) + 1e-5f);
        float le[NE];
#pragma unroll
        for (int e = 0; e < NE; e++) le[e] = 0.0f;
        u16* h2p = h2 + (size_t)t * DM;
#pragma unroll
        for (int i = 0; i < 12; i++) {
            int c = lane + 64 * i;
            float h = (xv[i] - mu) * rs * g2s[c] + b2s[c];
            h2p[c] = f2bf(h);
#pragma unroll
            for (int e = 0; e < NE; e++) le[e] += h * wgs[e * DM + c];
        }
#pragma unroll
        for (int e = 0; e < NE; e++) {
#pragma unroll
            for (int m = 1; m < 64; m <<= 1) le[e] += __shfl_xor(le[e], m);
        }
        // all lanes hold bitwise-identical le[] (butterfly) -> uniform argmax
        float best = le[0] + bg[0]; int be = 0;
#pragma unroll
        for (int e = 1; e < NE; e++) {
            float q = le[e] + bg[e];
            if (q > best) { best = q; be = e; }   // strict > == first-max (jnp.argmax)
        }
        if (lane == 0) {
            int pos = atomicAdd(&cnt[be], 1);
            buck[be * T_TOK + pos] = t;
        }
        // out init: x2 + b2[be]  (gemm2 atomicAdds the MoE matmul on top)
        float* op = out + (size_t)t * DM;
        const float* bp = b2moe + (size_t)be * DM;
#pragma unroll
        for (int i = 0; i < 12; i++) {
            int c = lane + 64 * i;
            op[c] = xv[i] + bp[c];
        }
    }
}

// ---------------- K2: grouped GEMM1 + gelu: hmid = gelu(h2 @ W1[e] + b1[e]) ----------------
// BM=128, BN=64, BK=64; 4 waves, wave -> 32-row strip x 64 cols.
// Depth-2 register prefetch + raw barriers (no vmcnt drain).
__global__ __launch_bounds__(256, 3) void k_moe_gemm1(
        const u16* __restrict__ h2, const float* __restrict__ W1,
        const float* __restrict__ b1, const int* __restrict__ cnt,
        const int* __restrict__ buck, u16* __restrict__ hmid) {
    int nt = blockIdx.x, e = blockIdx.y, mt = blockIdx.z;
    int cnte = cnt[e];
    int m0 = mt * 128;
    if (m0 >= cnte) return;
    int n0 = nt * 64;
    const float* W1e = W1 + (size_t)e * DM * FF;
    __shared__ __align__(16) u16 As[128 * 72];   // 18 KB
    __shared__ __align__(16) u16 Bs[64 * 72];    // 9 KB, [n][k]
    int tid = threadIdx.x, lane = tid & 63, wid = tid >> 6;

    // A staging: row = tid>>3 (+32j), col-chunk = tid&7. Clamped (unconditional).
    int arow = tid >> 3, ac = tid & 7;
    int atok[4];
#pragma unroll
    for (int j = 0; j < 4; j++) {
        int i = m0 + arow + 32 * j;
        if (i >= cnte) i = cnte - 1;           // garbage rows, never stored
        atok[j] = buck[e * T_TOK + i];
    }
    int bn = tid & 63, bkg = tid >> 6;

    f32x4_t acc[2][4];
#pragma unroll
    for (int mi = 0; mi < 2; mi++)
#pragma unroll
        for (int ni = 0; ni < 4; ni++) acc[mi][ni] = (f32x4_t){0.f, 0.f, 0.f, 0.f};

    bf16x8_t aP[4], aQ[4];
    float bP[16], bQ[16];

#define G_LOAD(SA, SB, KT) { \
    int k0_ = (KT) * 64; \
    _Pragma("unroll") \
    for (int j = 0; j < 4; j++) \
        SA[j] = *(const bf16x8_t*)&h2[(size_t)atok[j] * DM + k0_ + ac * 8]; \
    const float* bp_ = W1e + (size_t)(k0_ + bkg * 16) * FF + n0 + bn; \
    _Pragma("unroll") \
    for (int kk = 0; kk < 16; kk++) SB[kk] = bp_[(size_t)kk * FF]; \
}
#define STORE_LDS(SA, SB) { \
    _Pragma("unroll") \
    for (int j = 0; j < 4; j++) \
        *(bf16x8_t*)&As[(arow + 32 * j) * 72 + ac * 8] = SA[j]; \
    bf16x8_t p0_, p1_; \
    _Pragma("unroll") \
    for (int kk = 0; kk < 8; kk++) { \
        p0_[kk] = (short)f2bf(SB[kk]); \
        p1_[kk] = (short)f2bf(SB[kk + 8]); \
    } \
    *(bf16x8_t*)&Bs[bn * 72 + bkg * 16] = p0_; \
    *(bf16x8_t*)&Bs[bn * 72 + bkg * 16 + 8] = p1_; \
}
#define MFMA_TILE() { \
    int lr_ = lane & 15, q_ = lane >> 4; \
    _Pragma("unroll") \
    for (int s = 0; s < 2; s++) { \
        bf16x8_t af[2], bfr[4]; \
        _Pragma("unroll") \
        for (int mi = 0; mi < 2; mi++) \
            af[mi] = *(const bf16x8_t*)&As[(wid * 32 + mi * 16 + lr_) * 72 + s * 32 + q_ * 8]; \
        _Pragma("unroll") \
        for (int ni = 0; ni < 4; ni++) \
            bfr[ni] = *(const bf16x8_t*)&Bs[(ni * 16 + lr_) * 72 + s * 32 + q_ * 8]; \
        _Pragma("unroll") \
        for (int mi = 0; mi < 2; mi++) \
            _Pragma("unroll") \
            for (int ni = 0; ni < 4; ni++) \
                acc[mi][ni] = __builtin_amdgcn_mfma_f32_16x16x32_bf16( \
                    af[mi], bfr[ni], acc[mi][ni], 0, 0, 0); \
    } \
}
// one k-tile phase: raw barriers; own-wave lgkmcnt(0) after stores; prefetch
// set stays in flight across barriers (compiler emits counted vmcnt for the
// reg->LDS dependency only).
#define PHASE(SA, SB, PKT) { \
    SFENCE(); RAW_BAR(); SFENCE(); \
    STORE_LDS(SA, SB) \
    asm volatile("s_waitcnt lgkmcnt(0)" ::: "memory"); \
    SFENCE(); RAW_BAR(); SFENCE(); \
    if ((PKT) < 12) G_LOAD(SA, SB, PKT) \
    MFMA_TILE() \
}

    G_LOAD(aP, bP, 0)
    G_LOAD(aQ, bQ, 1)
    for (int kt = 0; kt < 12; kt += 2) {
        PHASE(aP, bP, kt + 2)
        PHASE(aQ, bQ, kt + 3)
    }
#undef G_LOAD
#undef STORE_LDS
#undef MFMA_TILE
#undef PHASE

    // epilogue: bias + gelu, scatter by token id
    int lr = lane & 15, q = lane >> 4;
    float bias[4];
#pragma unroll
    for (int ni = 0; ni < 4; ni++) bias[ni] = b1[(size_t)e * FF + n0 + ni * 16 + lr];
#pragma unroll
    for (int mi = 0; mi < 2; mi++) {
#pragma unroll
        for (int r = 0; r < 4; r++) {
            int i = m0 + wid * 32 + mi * 16 + q * 4 + r;
            if (i < cnte) {
                int t = buck[e * T_TOK + i];
                size_t base = (size_t)t * FF + n0;
#pragma unroll
                for (int ni = 0; ni < 4; ni++) {
                    float vv = acc[mi][ni][r] + bias[ni];
                    hmid[base + ni * 16 + lr] = f2bf(gelu_f(vv));
                }
            }
        }
    }
}

// ---------------- K3: grouped GEMM2 split-K x4: out += hmid @ W2[e] ----------------
// BM=128, BN=64, BK=64, K-chunk = FF/4 = 768. z = mt*4 + kc. Depth-2 prefetch,
// raw barriers.
__global__ __launch_bounds__(256, 3) void k_moe_gemm2(
        const u16* __restrict__ hmid, const float* __restrict__ W2,
        const int* __restrict__ cnt, const int* __restrict__ buck,
        float* __restrict__ out) {
    int nt = blockIdx.x, e = blockIdx.y, z = blockIdx.z;
    int kc = z & 3, mt = z >> 2;
    int cnte = cnt[e];
    int m0 = mt * 128;
    if (m0 >= cnte) return;
    int n0 = nt * 64;
    int kbase = kc * (FF / 4);
    const float* W2e = W2 + (size_t)e * FF * DM;
    __shared__ __align__(16) u16 As[128 * 72];
    __shared__ __align__(16) u16 Bs[64 * 72];
    int tid = threadIdx.x, lane = tid & 63, wid = tid >> 6;

    int arow = tid >> 3, ac = tid & 7;
    int atok[4];
#pragma unroll
    for (int j = 0; j < 4; j++) {
        int i = m0 + arow + 32 * j;
        if (i >= cnte) i = cnte - 1;           // garbage rows, never stored
        atok[j] = buck[e * T_TOK + i];
    }
    int bn = tid & 63, bkg = tid >> 6;

    f32x4_t acc[2][4];
#pragma unroll
    for (int mi = 0; mi < 2; mi++)
#pragma unroll
        for (int ni = 0; ni < 4; ni++) acc[mi][ni] = (f32x4_t){0.f, 0.f, 0.f, 0.f};

    bf16x8_t aP[4], aQ[4];
    float bP[16], bQ[16];

#define G_LOAD(SA, SB, KT) { \
    int k0_ = kbase + (KT) * 64; \
    _Pragma("unroll") \
    for (int j = 0; j < 4; j++) \
        SA[j] = *(const bf16x8_t*)&hmid[(size_t)atok[j] * FF + k0_ + ac * 8]; \
    const float* bp_ = W2e + (size_t)(k0_ + bkg * 16) * DM + n0 + bn; \
    _Pragma("unroll") \
    for (int kk = 0; kk < 16; kk++) SB[kk] = bp_[(size_t)kk * DM]; \
}
#define STORE_LDS(SA, SB) { \
    _Pragma("unroll") \
    for (int j = 0; j < 4; j++) \
        *(bf16x8_t*)&As[(arow + 32 * j) * 72 + ac * 8] = SA[j]; \
    bf16x8_t p0_, p1_; \
    _Pragma("unroll") \
    for (int kk = 0; kk < 8; kk++) { \
        p0_[kk] = (short)f2bf(SB[kk]); \
        p1_[kk] = (short)f2bf(SB[kk + 8]); \
    } \
    *(bf16x8_t*)&Bs[bn * 72 + bkg * 16] = p0_; \
    *(bf16x8_t*)&Bs[bn * 72 + bkg * 16 + 8] = p1_; \
}
#define MFMA_TILE() { \
    int lr_ = lane & 15, q_ = lane >> 4; \
    _Pragma("unroll") \
    for (int s = 0; s < 2; s++) { \
        bf16x8_t af[2], bfr[4]; \
        _Pragma("unroll") \
        for (int mi = 0; mi < 2; mi++) \
            af[mi] = *(const bf16x8_t*)&As[(wid * 32 + mi * 16 + lr_) * 72 + s * 32 + q_ * 8]; \
        _Pragma("unroll") \
        for (int ni = 0; ni < 4; ni++) \
            bfr[ni] = *(const bf16x8_t*)&Bs[(ni * 16 + lr_) * 72 + s * 32 + q_ * 8]; \
        _Pragma("unroll") \
        for (int mi = 0; mi < 2; mi++) \
            _Pragma("unroll") \
            for (int ni = 0; ni < 4; ni++) \
                acc[mi][ni] = __builtin_amdgcn_mfma_f32_16x16x32_bf16( \
                    af[mi], bfr[ni], acc[mi][ni], 0, 0, 0); \
    } \
}
#define PHASE(SA, SB, PKT) { \
    SFENCE(); RAW_BAR(); SFENCE(); \
    STORE_LDS(SA, SB) \
    asm volatile("s_waitcnt lgkmcnt(0)" ::: "memory"); \
    SFENCE(); RAW_BAR(); SFENCE(); \
    if ((PKT) < 12) G_LOAD(SA, SB, PKT) \
    MFMA_TILE() \
}

    G_LOAD(aP, bP, 0)
    G_LOAD(aQ, bQ, 1)
    for (int kt = 0; kt < 12; kt += 2) {
        PHASE(aP, bP, kt + 2)
        PHASE(aQ, bQ, kt + 3)
    }
#undef G_LOAD
#undef STORE_LDS
#undef MFMA_TILE
#undef PHASE

    // epilogue: atomicAdd partials into out (out pre-initialized with x2 + b2[e])
    int lr = lane & 15, q = lane >> 4;
#pragma unroll
    for (int mi = 0; mi < 2; mi++) {
#pragma unroll
        for (int r = 0; r < 4; r++) {
            int i = m0 + wid * 32 + mi * 16 + q * 4 + r;
            if (i < cnte) {
                int t = buck[e * T_TOK + i];
                size_t base = (size_t)t * DM + n0;
#pragma unroll
                for (int ni = 0; ni < 4; ni++)
                    atomicAdd(&out[base + ni * 16 + lr], acc[mi][ni][r]);
            }
        }
    }
}

extern "C" void kernel_launch(void* const* d_in, const int* in_sizes, int n_in,
                              void* d_out, int out_size, void* d_ws, size_t ws_size,
                              hipStream_t stream) {
    const float* x    = (const float*)d_in[0];
    const float* ln1g = (const float*)d_in[1];
    const float* ln1b = (const float*)d_in[2];
    // d_in[3..6] = Wq,bq,Wk,bk: dead code
    const float* Wv   = (const float*)d_in[7];
    const float* bv   = (const float*)d_in[8];
    const float* ln2g = (const float*)d_in[9];
    const float* ln2b = (const float*)d_in[10];
    const float* Wg   = (const float*)d_in[11];
    const float* bg   = (const float*)d_in[12];
    const float* W1   = (const float*)d_in[13];
    const float* b1   = (const float*)d_in[14];
    const float* W2   = (const float*)d_in[15];
    const float* b2   = (const float*)d_in[16];

    char* ws = (char*)d_ws;
    int*   cnt  = (int*)(ws + OFF_CNT);
    int*   buck = (int*)(ws + OFF_BUCK);
    u16*   h2   = (u16*)(ws + OFF_H2);
    u16*   hmid = (u16*)(ws + OFF_HMID);
    float* out  = (float*)d_out;

    hipMemsetAsync(cnt, 0, NE * sizeof(int), stream);
    k_front<<<T_TOK / 8, 256, 0, stream>>>(x, ln1g, ln1b, Wv, bv, ln2g, ln2b,
                                           Wg, bg, b2, h2, out, cnt, buck);
    k_moe_gemm1<<<dim3(FF / 64, NE, 13), 256, 0, stream>>>(h2, W1, b1, cnt, buck, hmid);
    k_moe_gemm2<<<dim3(DM / 64, NE, 52), 256, 0, stream>>>(hmid, W2, cnt, buck, out);
}